// Round 1
// baseline (90.546 us; speedup 1.0000x reference)
//
#include <hip/hip_runtime.h>

// B=16, N=2048, S=SO=12, K=32.
// out[b,i,k,s] = softmax_k( leaky_relu( es[b,i] + ed[b,j] ) ) * x[b,j,s],  j=idx[b,i,k]
// es[n] = x[n,:]·(W@a[:12]),  ed[n] = x[n,:]·(W@a[12:])  — per-NODE, so precompute
// once (32768 dots) instead of per-(i,k) (2.1M dots). x rows repacked to 16-float
// (64 B) stride so each scattered gather row sits in exactly one cache line.

#define GAT_N 2048
#define GAT_ALPHA 0.5f
#define PPB 8   // pairs per 256-thread block

// ---------------- Kernel A: per-node precompute + row repack ----------------
__global__ __launch_bounds__(256) void gat_precomp(
    const float* __restrict__ x,   // [B*N, 12]
    const float* __restrict__ W,   // [12,12]
    const float* __restrict__ a,   // [24]
    float*       __restrict__ xp,  // [B*N, 16]  padded rows
    float*       __restrict__ es,  // [B*N]
    float*       __restrict__ ed)  // [B*N]
{
    __shared__ float wvec[24];          // w_src | w_dst
    __shared__ float rows[256 * 12];    // 12 KB row staging
    const int tid = threadIdx.x;

    if (tid < 24) {
        const int s = tid % 12;
        const float* av = a + (tid < 12 ? 0 : 12);
        float acc = 0.f;
        #pragma unroll
        for (int t = 0; t < 12; ++t) acc += W[s * 12 + t] * av[t];
        wvec[tid] = acc;
    }
    // coalesced stage of 256 rows (12 KB)
    const float4* g4 = (const float4*)(x + (size_t)blockIdx.x * 256 * 12);
    float4* l4 = (float4*)rows;
    #pragma unroll
    for (int r = 0; r < 3; ++r) l4[tid + 256 * r] = g4[tid + 256 * r];
    __syncthreads();

    const int n = blockIdx.x * 256 + tid;
    const float* row = rows + tid * 12;
    float s0 = 0.f, s1 = 0.f;
    #pragma unroll
    for (int t = 0; t < 12; ++t) {
        s0 += row[t] * wvec[t];
        s1 += row[t] * wvec[12 + t];
    }
    es[n] = s0;
    ed[n] = s1;

    // coalesced write of padded rows: [256][16] floats = 1024 float4 per block
    float4* o4 = (float4*)(xp + (size_t)blockIdx.x * 256 * 16);
    #pragma unroll
    for (int c = 0; c < 4; ++c) {
        const int g  = tid + 256 * c;
        const int r  = g >> 2;
        const int pc = g & 3;
        float4 v = make_float4(0.f, 0.f, 0.f, 0.f);
        if (pc < 3) v = *(const float4*)(rows + r * 12 + pc * 4);
        o4[g] = v;
    }
}

// ---------------- Kernel B: gather + softmax + product ----------------
__global__ __launch_bounds__(256) void gat_main(
    const float* __restrict__ xp,     // [B*N, 16]
    const float* __restrict__ es_arr, // [B*N]
    const float* __restrict__ ed_arr, // [B*N]
    const int*   __restrict__ idx,    // [B*N, 32]
    float*       __restrict__ out)    // [B*N, 32, 12]
{
    __shared__ float stage[PPB * 384];               // 12 KB output staging
    const int tid  = threadIdx.x;
    const int p    = tid >> 5;                       // pair slot in block
    const int pair = blockIdx.x * PPB + p;           // b*N + i
    const int k    = tid & 31;                       // neighbor slot

    const int j   = idx[(size_t)pair * 32 + k];
    const int nbr = (pair & ~(GAT_N - 1)) + j;       // b*N + j

    // one-line gather of neighbor row (64 B aligned)
    const float4* rowj = (const float4*)(xp + (size_t)nbr * 16);
    const float4 n0 = rowj[0], n1 = rowj[1], n2 = rowj[2];

    // attention logit from precomputed per-node scalars
    const float e  = es_arr[pair] + ed_arr[nbr];
    float sc = e > 0.f ? e : GAT_ALPHA * e;

    // softmax over 32 lanes (half-wave segment)
    float m = sc;
    #pragma unroll
    for (int off = 16; off; off >>= 1) m = fmaxf(m, __shfl_xor(m, off, 32));
    const float ex = __expf(sc - m);
    float sum = ex;
    #pragma unroll
    for (int off = 16; off; off >>= 1) sum += __shfl_xor(sum, off, 32);
    const float att = ex / sum;

    // stage att * neigh into LDS (3x ds_write_b128 per lane)
    float4* st = (float4*)(stage + p * 384 + k * 12);
    st[0] = make_float4(att * n0.x, att * n0.y, att * n0.z, att * n0.w);
    st[1] = make_float4(att * n1.x, att * n1.y, att * n1.z, att * n1.w);
    st[2] = make_float4(att * n2.x, att * n2.y, att * n2.z, att * n2.w);
    __syncthreads();

    // block-wide coalesced flush: 8*384 floats = 768 float4, 3 per thread
    const float4* sm4 = (const float4*)stage;
    float4* o4 = (float4*)(out + (size_t)blockIdx.x * PPB * 384);
    #pragma unroll
    for (int r = 0; r < 3; ++r) o4[tid + 256 * r] = sm4[tid + 256 * r];
}

// ---------------- Fallback: previous verified single-kernel path ----------------
__global__ __launch_bounds__(256) void gat_fused(
    const float* __restrict__ x, const float* __restrict__ W,
    const float* __restrict__ a, const int* __restrict__ idx,
    float* __restrict__ out)
{
    __shared__ float wvec[24];
    __shared__ float stage[PPB * 384];
    const int tid = threadIdx.x;

    if (tid < 24) {
        const int s = tid % 12;
        const float* av = a + (tid < 12 ? 0 : 12);
        float acc = 0.f;
        #pragma unroll
        for (int t = 0; t < 12; ++t) acc += W[s * 12 + t] * av[t];
        wvec[tid] = acc;
    }
    __syncthreads();

    const int p    = tid >> 5;
    const int pair = blockIdx.x * PPB + p;
    const int k    = tid & 31;

    const float4* rowi = (const float4*)(x + (size_t)pair * 12);
    const float4 i0 = rowi[0], i1 = rowi[1], i2 = rowi[2];
    const float e_src =
        i0.x*wvec[0] + i0.y*wvec[1] + i0.z*wvec[2]  + i0.w*wvec[3] +
        i1.x*wvec[4] + i1.y*wvec[5] + i1.z*wvec[6]  + i1.w*wvec[7] +
        i2.x*wvec[8] + i2.y*wvec[9] + i2.z*wvec[10] + i2.w*wvec[11];

    const int j   = idx[(size_t)pair * 32 + k];
    const int nbr = (pair & ~(GAT_N - 1)) + j;
    const float4* rowj = (const float4*)(x + (size_t)nbr * 12);
    const float4 n0 = rowj[0], n1 = rowj[1], n2 = rowj[2];
    const float e_dst =
        n0.x*wvec[12] + n0.y*wvec[13] + n0.z*wvec[14] + n0.w*wvec[15] +
        n1.x*wvec[16] + n1.y*wvec[17] + n1.z*wvec[18] + n1.w*wvec[19] +
        n2.x*wvec[20] + n2.y*wvec[21] + n2.z*wvec[22] + n2.w*wvec[23];

    float sc = e_src + e_dst;
    sc = sc > 0.f ? sc : GAT_ALPHA * sc;
    float m = sc;
    #pragma unroll
    for (int off = 16; off; off >>= 1) m = fmaxf(m, __shfl_xor(m, off, 32));
    const float ex = __expf(sc - m);
    float sum = ex;
    #pragma unroll
    for (int off = 16; off; off >>= 1) sum += __shfl_xor(sum, off, 32);
    const float att = ex / sum;

    float4* st = (float4*)(stage + p * 384 + k * 12);
    st[0] = make_float4(att * n0.x, att * n0.y, att * n0.z, att * n0.w);
    st[1] = make_float4(att * n1.x, att * n1.y, att * n1.z, att * n1.w);
    st[2] = make_float4(att * n2.x, att * n2.y, att * n2.z, att * n2.w);
    __syncthreads();

    const float4* sm4 = (const float4*)stage;
    float4* o4 = (float4*)(out + (size_t)blockIdx.x * PPB * 384);
    #pragma unroll
    for (int r = 0; r < 3; ++r) o4[tid + 256 * r] = sm4[tid + 256 * r];
}

extern "C" void kernel_launch(void* const* d_in, const int* in_sizes, int n_in,
                              void* d_out, int out_size, void* d_ws, size_t ws_size,
                              hipStream_t stream) {
    // inputs: fushed_features (unused), input_data, W, a, idx
    const float* x   = (const float*)d_in[1];
    const float* W   = (const float*)d_in[2];
    const float* a   = (const float*)d_in[3];
    const int*   idx = (const int*)d_in[4];
    float* out = (float*)d_out;

    const int pairs  = in_sizes[1] / 12;   // B*N = 32768 nodes
    const int blocks = pairs / PPB;        // 4096

    const size_t xp_bytes = (size_t)pairs * 16 * sizeof(float); // 2 MB
    const size_t e_bytes  = (size_t)pairs * sizeof(float);      // 128 KB each
    if (ws_size >= xp_bytes + 2 * e_bytes) {
        float* xp = (float*)d_ws;
        float* es = xp + (size_t)pairs * 16;
        float* ed = es + pairs;
        gat_precomp<<<pairs / 256, 256, 0, stream>>>(x, W, a, xp, es, ed);
        gat_main<<<blocks, 256, 0, stream>>>(xp, es, ed, idx, out);
    } else {
        gat_fused<<<blocks, 256, 0, stream>>>(x, W, a, idx, out);
    }
}